// Round 6
// baseline (355.306 us; speedup 1.0000x reference)
//
#include <hip/hip_runtime.h>
#include <hip/hip_bf16.h>
#include <stdint.h>

#define S_LEN   2048
#define DIN     2048
#define NHEADS  32
#define HDIM    64
#define NKV     8

typedef __bf16 bf16x8 __attribute__((ext_vector_type(8)));
typedef float  f32x4  __attribute__((ext_vector_type(4)));

#define AS1(p) ((__attribute__((address_space(1))) void*)(void*)(p))
#define AS3(p) ((__attribute__((address_space(3))) void*)(p))
#define MFMA_BF16 __builtin_amdgcn_mfma_f32_16x16x32_bf16

#if __has_builtin(__builtin_amdgcn_exp2f)
#define EXP2F(x) __builtin_amdgcn_exp2f(x)
#else
#define EXP2F(x) exp2f(x)
#endif

static __device__ __forceinline__ unsigned short f2bf(float f) {
  unsigned int x = __float_as_uint(f);
  return (unsigned short)((x + 0x7fffu + ((x >> 16) & 1u)) >> 16);
}
static __device__ __forceinline__ float bf2f(unsigned short u) {
  return __uint_as_float((unsigned int)u << 16);
}

// ---------------- cast x (fp32 -> bf16), vectorized ----------------
__global__ __launch_bounds__(256) void cast_x_kernel(const float* __restrict__ x,
                                                     unsigned short* __restrict__ xb, int n4) {
  int i = blockIdx.x * 256 + threadIdx.x;
  if (i >= n4) return;
  float4 f = ((const float4*)x)[i];
  ushort4 o = make_ushort4(f2bf(f.x), f2bf(f.y), f2bf(f.z), f2bf(f.w));
  ((ushort4*)xb)[i] = o;
}

// ---------------- transpose + cast: src fp32 [K][N] -> dst bf16 [N][K] ----------------
__global__ __launch_bounds__(256) void transpose_cast(const float* __restrict__ src,
                                                      unsigned short* __restrict__ dst,
                                                      int K, int N) {
  __shared__ float t[32][33];
  int n0 = blockIdx.x * 32, k0 = blockIdx.y * 32;
  int x = threadIdx.x, y = threadIdx.y;
  #pragma unroll
  for (int j = 0; j < 32; j += 8)
    t[y + j][x] = src[(size_t)(k0 + y + j) * N + n0 + x];
  __syncthreads();
  #pragma unroll
  for (int j = 0; j < 32; j += 8)
    dst[(size_t)(n0 + y + j) * K + k0 + x] = f2bf(t[x][y + j]);
}

// ---------------- fused W transpose: [Wq|Wk|Wv] -> wcat bf16 [3072][2048] ----------------
__global__ __launch_bounds__(256) void transpose_cast_wqkv(const float* __restrict__ Wq,
                                                           const float* __restrict__ Wk,
                                                           const float* __restrict__ Wv,
                                                           unsigned short* __restrict__ dst) {
  __shared__ float t[32][33];
  int n0 = blockIdx.x * 32, k0 = blockIdx.y * 32;   // n0 in [0,3072)
  const float* src; int col0, srcN;
  if (n0 < 2048)      { src = Wq; col0 = n0;        srcN = 2048; }
  else if (n0 < 2560) { src = Wk; col0 = n0 - 2048; srcN = 512; }
  else                { src = Wv; col0 = n0 - 2560; srcN = 512; }
  int x = threadIdx.x, y = threadIdx.y;
  #pragma unroll
  for (int j = 0; j < 32; j += 8)
    t[y + j][x] = src[(size_t)(k0 + y + j) * srcN + col0 + x];
  __syncthreads();
  #pragma unroll
  for (int j = 0; j < 32; j += 8)
    dst[(size_t)(n0 + y + j) * 2048 + k0 + x] = f2bf(t[x][y + j]);
}

// ---------------- bf16 NT GEMM: C[M][N] = A[M][K] * Bt[N][K]^T (fp32 or bf16 out) ----
// m97 structure + XOR-swizzled LDS. Still used for the Wo GEMM.
template <typename OutT>
__global__ __launch_bounds__(256) void gemm_nt(const unsigned short* __restrict__ A,
                                               const unsigned short* __restrict__ Bt,
                                               OutT* __restrict__ C,
                                               int M, int N, int K) {
  __shared__ alignas(16) unsigned short As[128 * 32];
  __shared__ alignas(16) unsigned short Bs[128 * 32];
  const int tid = threadIdx.x;
  const int wave = tid >> 6, lane = tid & 63;
  const int g = lane >> 4, c = lane & 15;
  const int m0 = blockIdx.y * 128, n0 = blockIdx.x * 128;
  const int wm = (wave & 1) * 64, wn = (wave >> 1) * 64;

  f32x4 acc[4][4] = {};

  const int ch0 = wave * 2;
  const int p0 = ch0 * 64 + lane, p1 = p0 + 64;
  const int r0 = p0 >> 2, gc0 = ((p0 & 3) ^ ((r0 >> 1) & 3)) * 8;
  const int r1 = p1 >> 2, gc1 = ((p1 & 3) ^ ((r1 >> 1) & 3)) * 8;
  const unsigned short* a0 = A + (size_t)(m0 + r0) * K + gc0;
  const unsigned short* a1 = A + (size_t)(m0 + r1) * K + gc1;
  const unsigned short* b0 = Bt + (size_t)(n0 + r0) * K + gc0;
  const unsigned short* b1 = Bt + (size_t)(n0 + r1) * K + gc1;
  const int fswz = (c >> 1) & 3;   // f(row) for consumer rows (wm,i*16 are mult of 16)

  for (int k0 = 0; k0 < K; k0 += 32) {
    __syncthreads();
    __builtin_amdgcn_global_load_lds(AS1(a0 + k0), AS3(As + ch0 * 512), 16, 0, 0);
    __builtin_amdgcn_global_load_lds(AS1(a1 + k0), AS3(As + ch0 * 512 + 512), 16, 0, 0);
    __builtin_amdgcn_global_load_lds(AS1(b0 + k0), AS3(Bs + ch0 * 512), 16, 0, 0);
    __builtin_amdgcn_global_load_lds(AS1(b1 + k0), AS3(Bs + ch0 * 512 + 512), 16, 0, 0);
    __builtin_amdgcn_s_waitcnt(0);
    __syncthreads();

    bf16x8 af[4], bfr[4];
    #pragma unroll
    for (int i = 0; i < 4; i++)
      af[i] = *(const bf16x8*)(As + (wm + i * 16 + c) * 32 + (g ^ fswz) * 8);
    #pragma unroll
    for (int j = 0; j < 4; j++)
      bfr[j] = *(const bf16x8*)(Bs + (wn + j * 16 + c) * 32 + (g ^ fswz) * 8);
    #pragma unroll
    for (int i = 0; i < 4; i++)
      #pragma unroll
      for (int j = 0; j < 4; j++)
        acc[i][j] = MFMA_BF16(af[i], bfr[j], acc[i][j], 0, 0, 0);
  }

  #pragma unroll
  for (int i = 0; i < 4; i++)
    #pragma unroll
    for (int j = 0; j < 4; j++)
      #pragma unroll
      for (int r = 0; r < 4; r++) {
        size_t idx = (size_t)(m0 + wm + i * 16 + g * 4 + r) * N + n0 + wn + j * 16 + c;
        if constexpr (sizeof(OutT) == 2) C[idx] = f2bf(acc[i][j][r]);
        else                             C[idx] = acc[i][j][r];
      }
}

// ---------------- QKV GEMM: 256x256 tile, BK=32, 4-slot LDS ring, counted vmcnt ----
// The m97 structure drains vmcnt(0) at every barrier (the ~20% structural stall,
// MfmaUtil 30%). This kernel keeps 8 loads in flight ACROSS barriers (T3+T4):
// phase t: stage tile t+3 -> slot (t+3)&3 (readers of that slot finished at the
// phase t-1 barrier); ds_read tile t from slot t&3 (its stage was confirmed by
// the vmcnt at phase t-1); 32 MFMA under setprio; s_waitcnt vmcnt(8) (tile t+1
// landed, tiles t+2/t+3 still in flight); raw s_barrier. Tail: vmcnt(4)/(0).
// LDS swizzle byte^=((row&3)<<4) via pre-permuted per-lane GLOBAL source with
// linear LDS dest (rule 21); ds_read_b128 lands 2 lanes/16B-slot = free.
// M=4096, N=3072, K=2048 fixed; grid (12,16) x 512 thr; LDS 128 KiB.
__global__ __launch_bounds__(512, 2) void gemm_qkv_ring(const unsigned short* __restrict__ A,
                                                        const unsigned short* __restrict__ Bt,
                                                        unsigned short* __restrict__ C) {
  constexpr int K = 2048, N = 3072, NT = 64;            // NT = K/32
  __shared__ alignas(16) unsigned short As[4][8192];    // 4 x 16 KiB (256 rows x 32 k)
  __shared__ alignas(16) unsigned short Bs[4][8192];
  const int tid = threadIdx.x;
  const int wave = tid >> 6, lane = tid & 63;
  const int g = lane >> 4, c = lane & 15;
  const int m0 = blockIdx.y * 256, n0 = blockIdx.x * 256;
  const int wr = wave >> 2, wc = wave & 3;              // 2M x 4N wave grid

  // staging: linear LDS dest P = ch*8192 + tid*16 bytes; logical L = P ^ swz(P);
  // source element = (row L>>6, byte L&63) of the 256x32 tile (row-major, 64B rows)
  const unsigned short* sA[2];
  const unsigned short* sB[2];
  #pragma unroll
  for (int ch = 0; ch < 2; ch++) {
    int P = ch * 8192 + tid * 16;
    int L = P ^ (((P >> 6) & 3) << 4);
    int r = L >> 6, cw = (L & 63) >> 1;
    sA[ch] = A + (size_t)(m0 + r) * K + cw;
    sB[ch] = Bt + (size_t)(n0 + r) * K + cw;
  }

  // fragment read bases (ushort units within a slot); row&3 == c&3 for our rows
  const int swzr = (g * 16) ^ ((c & 3) << 4);
  const int baseA = ((wr * 128 + c) * 64 + swzr) >> 1;
  const int baseB = ((wc * 64 + c) * 64 + swzr) >> 1;

  f32x4 acc[8][4] = {};

  auto STAGE = [&](int t) {
    const int s = t & 3;
    const int ko = t * 32;
    #pragma unroll
    for (int ch = 0; ch < 2; ch++) {
      __builtin_amdgcn_global_load_lds(AS1(sA[ch] + ko), AS3(&As[s][ch * 4096 + wave * 512]), 16, 0, 0);
      __builtin_amdgcn_global_load_lds(AS1(sB[ch] + ko), AS3(&Bs[s][ch * 4096 + wave * 512]), 16, 0, 0);
    }
  };

  STAGE(0); STAGE(1); STAGE(2);                  // 12 loads in flight
  asm volatile("s_waitcnt vmcnt(8)" ::: "memory");   // tile 0 landed
  __builtin_amdgcn_s_barrier();

  for (int t = 0; t < NT; t++) {
    if (t + 3 < NT) STAGE(t + 3);                // slot (t+3)&3: readers done at t-1 barrier
    const int s = t & 3;
    bf16x8 af[8], bf[4];
    #pragma unroll
    for (int i = 0; i < 8; i++) af[i] = *(const bf16x8*)(&As[s][baseA + i * 512]);
    #pragma unroll
    for (int j = 0; j < 4; j++) bf[j] = *(const bf16x8*)(&Bs[s][baseB + j * 512]);
    __builtin_amdgcn_s_setprio(1);
    #pragma unroll
    for (int i = 0; i < 8; i++)
      #pragma unroll
      for (int j = 0; j < 4; j++)
        acc[i][j] = MFMA_BF16(af[i], bf[j], acc[i][j], 0, 0, 0);
    __builtin_amdgcn_s_setprio(0);
    if (t + 3 < NT)      asm volatile("s_waitcnt vmcnt(8)" ::: "memory");  // tile t+1 landed
    else if (t + 2 < NT) asm volatile("s_waitcnt vmcnt(4)" ::: "memory");
    else                 asm volatile("s_waitcnt vmcnt(0)" ::: "memory");
    __builtin_amdgcn_s_barrier();
  }

  // C write: row = m0 + wr*128 + i*16 + g*4 + r, col = n0 + wc*64 + j*16 + c
  #pragma unroll
  for (int i = 0; i < 8; i++)
    #pragma unroll
    for (int j = 0; j < 4; j++)
      #pragma unroll
      for (int r = 0; r < 4; r++) {
        size_t idx = (size_t)(m0 + wr * 128 + i * 16 + g * 4 + r) * N + n0 + wc * 64 + j * 16 + c;
        C[idx] = f2bf(acc[i][j][r]);
      }
}

// ---------------- RMSNorm + RoPE for Q and K heads (bf16 QKV input) ----------------
__global__ __launch_bounds__(256) void norm_rope(const unsigned short* __restrict__ QKV,
                                                 const float* __restrict__ cosb,
                                                 const float* __restrict__ sinb,
                                                 const float* __restrict__ q_scale,
                                                 const float* __restrict__ k_scale,
                                                 unsigned short* __restrict__ Qn,
                                                 unsigned short* __restrict__ Kn) {
  const int tid = threadIdx.x, w = tid >> 6, d = tid & 63;
  const float qs = q_scale[d], ks = k_scale[d];
  #pragma unroll
  for (int k = 0; k < 4; k++) {
    int task = blockIdx.x * 16 + w * 4 + k;
    const int hid = task % 40;
    const int row = task / 40;            // b*2048 + s
    const int b = row >> 11, s = row & 2047;
    float val, sc;
    if (hid < 32) {
      val = bf2f(QKV[(size_t)row * 3072 + hid * 64 + d]);
      sc = qs;
    } else {
      val = bf2f(QKV[(size_t)row * 3072 + 2048 + (hid - 32) * 64 + d]);
      sc = ks;
    }
    float v2 = val * val;
    #pragma unroll
    for (int off = 32; off; off >>= 1) v2 += __shfl_xor(v2, off);
    float t = val * (1.0f / sqrtf(v2 * (1.0f / 64.0f) + 1e-6f)) * sc;
    float partner = __shfl_xor(t, 32);
    float rot = (d < 32) ? -partner : partner;
    float o = t * cosb[s * 64 + d] + rot * sinb[s * 64 + d];
    if (hid < 32) o *= 0.18033688011112042f;   // fold softmax scale into Q
    unsigned short ob = f2bf(o);
    if (hid < 32) Qn[((size_t)(b * 32 + hid) * 2048 + s) * 64 + d] = ob;
    else          Kn[((size_t)(b * 8 + (hid - 32)) * 2048 + s) * 64 + d] = ob;
  }
}

// ---------------- V transpose: bf16 QKV V-cols -> Vt bf16 [b][kv][D][S] ----------------
__global__ __launch_bounds__(256) void v_transpose(const unsigned short* __restrict__ QKV,
                                                   unsigned short* __restrict__ Vt) {
  __shared__ unsigned int t[64][65];
  int bid = blockIdx.x;
  const int st = bid & 31, kv = (bid >> 5) & 7, b = bid >> 8;
  const int tid = threadIdx.x, lane = tid & 63, quad = tid >> 6;
  #pragma unroll
  for (int p = 0; p < 16; p++) {
    int sl = p * 4 + quad;
    t[sl][lane] = QKV[(size_t)(b * 2048 + st * 64 + sl) * 3072 + 2560 + kv * 64 + lane];
  }
  __syncthreads();
  size_t base = (size_t)(b * 8 + kv) * 64 * 2048;
  #pragma unroll
  for (int p = 0; p < 16; p++) {
    int dd = p * 4 + quad;
    Vt[base + (size_t)dd * 2048 + st * 64 + lane] = (unsigned short)t[lane][dd];
  }
}

// ---------------- causal flash attention v10 (unchanged from round 5) ----------------
__global__ __launch_bounds__(256, 3) void attn_kernel(const unsigned short* __restrict__ Qn,
                                                      const unsigned short* __restrict__ Kn,
                                                      const unsigned short* __restrict__ Vt,
                                                      unsigned short* __restrict__ Outv) {
  __shared__ alignas(16) unsigned short Ksh[2][4096];   // [buf][64 rows x 64 d]
  __shared__ alignas(16) unsigned short Vsh[2][4096];   // [buf][64 rows(d) x 64 kv]
  __shared__ alignas(16) char Psh[4][4352];             // per-wave P buffers

  const int tid = threadIdx.x, w = tid >> 6, lane = tid & 63;
  const int g = lane >> 4, c = lane & 15;
  const int cs = c & 7;
  const int rl = (lane >> 3) & 7;      // staging: row within 1KB chunk
  const int sl = lane & 7;             // staging: 16B slot within row
  const int swz = (sl ^ rl) << 3;      // pre-swizzled source column (elements)
  const int bid = blockIdx.x;                      // [0, 1024)
  const int qt = 63 - (bid >> 4);                  // longest blocks first
  const int rem = bid & 15;
  const int hg = rem & 7, b = rem >> 3;
  const int h = hg * 4 + w;
  const int Q0 = qt * 32;
  const unsigned short* Qp = Qn + ((size_t)(b * NHEADS + h) * S_LEN + Q0) * HDIM;
  const unsigned short* Kp = Kn + (size_t)(b * NKV + hg) * S_LEN * HDIM;
  const unsigned short* Vp = Vt + (size_t)(b * NKV + hg) * HDIM * S_LEN;  // [d][s]
  const int ntiles = (qt >> 1) + 1;
  char* PwB = Psh[w];                  // 32 rows x 128 B, swizzled

  // Q as B-operand: B[k=d][n=q], n = c, k = g*8+j (+t*32)
  bf16x8 bq[2][2];
  #pragma unroll
  for (int iq = 0; iq < 2; iq++)
    #pragma unroll
    for (int t = 0; t < 2; t++)
      bq[iq][t] = *(const bf16x8*)(Qp + (iq * 16 + c) * HDIM + t * 32 + g * 8);

  f32x4 OT[4][2] = {};          // O^T tiles: [dt][iq], row=d, col=q
  float lv[2] = {0.f, 0.f};     // per-lane l partials

  const int wr0 = w * 16;       // this wave's 16 staging rows

  // stage K rows [kv0+wr0, +16) and V^T rows [wr0, +16) of the kv window
  auto STAGE = [&](int kv0s, int bi) {
    #pragma unroll
    for (int q = 0; q < 2; q++) {
      const int rr = wr0 + q * 8;
      __builtin_amdgcn_global_load_lds(AS1(Kp + (size_t)(kv0s + rr + rl) * 64 + swz),
                                       AS3(&Ksh[bi][rr * 64]), 16, 0, 0);
      __builtin_amdgcn_global_load_lds(AS1(Vp + (size_t)(rr + rl) * 2048 + kv0s + swz),
                                       AS3(&Vsh[bi][rr * 64]), 16, 0, 0);
    }
  };

  STAGE(0, 0);
  __syncthreads();

  for (int ti = 0; ti < ntiles; ti++) {
    const int kv0 = ti * 64;
    const int cur = ti & 1;
    if (ti + 1 < ntiles) STAGE(kv0 + 64, cur ^ 1);

    const unsigned short* Kb = Ksh[cur];
    const unsigned short* Vb = Vsh[cur];

    // QK + softmax in two jt-pairs (Sx live = 16 regs)
    #pragma unroll
    for (int jb = 0; jb < 2; jb++) {
      bf16x8 akx[2][2];
      #pragma unroll
      for (int jt = 0; jt < 2; jt++)
        #pragma unroll
        for (int t = 0; t < 2; t++)
          akx[jt][t] = *(const bf16x8*)(Kb + ((jb * 2 + jt) * 16 + c) * 64 +
                                        (((t * 4 + g) ^ cs) << 3));
      f32x4 Sx[2][2] = {};
      #pragma unroll
      for (int t = 0; t < 2; t++)
        #pragma unroll
        for (int jt = 0; jt < 2; jt++)
          #pragma unroll
          for (int iq = 0; iq < 2; iq++)
            Sx[jt][iq] = MFMA_BF16(akx[jt][t], bq[iq][t], Sx[jt][iq], 0, 0, 0);

      if (ti == ntiles - 1) {   // only the final tile crosses the diagonal
        #pragma unroll
        for (int jt = 0; jt < 2; jt++)
          #pragma unroll
          for (int iq = 0; iq < 2; iq++)
            #pragma unroll
            for (int r = 0; r < 4; r++) {
              int kv = kv0 + (jb * 2 + jt) * 16 + g * 4 + r;
              int q  = Q0 + iq * 16 + c;
              if (kv > q) Sx[jt][iq][r] = -1e30f;
            }
      }

      // fixed-max softmax: p = exp2(s); accumulate l; pack P -> LDS (swizzled)
      #pragma unroll
      for (int jt = 0; jt < 2; jt++)
        #pragma unroll
        for (int iq = 0; iq < 2; iq++) {
          f32x4 p;
          #pragma unroll
          for (int r = 0; r < 4; r++) p[r] = EXP2F(Sx[jt][iq][r]);
          lv[iq] += (p[0] + p[1]) + (p[2] + p[3]);
          uint32_t u0 = __float_as_uint(p[0]) + 0x8000u;
          uint32_t u1 = __float_as_uint(p[1]) + 0x8000u;
          uint32_t u2 = __float_as_uint(p[2]) + 0x8000u;
          uint32_t u3 = __float_as_uint(p[3]) + 0x8000u;
          uint32_t lo = __builtin_amdgcn_perm(u1, u0, 0x07060302u);
          uint32_t hi = __builtin_amdgcn_perm(u3, u2, 0x07060302u);
          int row = iq * 16 + c;                       // local q
          int bytecol = (jb * 2 + jt) * 32 + g * 8;    // kv-contiguous bytes
          uint32_t off = row * 128 + (((bytecol >> 4) ^ (row & 7)) << 4) + (bytecol & 15);
          *(uint2*)(PwB + off) = make_uint2(lo, hi);
        }
    }

    __builtin_amdgcn_s_waitcnt(0xC07F);        // lgkmcnt(0): P writes visible

    // PV per t-half: V from LDS, P as B-operand B[k=kv][n=q]
    #pragma unroll
    for (int t = 0; t < 2; t++) {
      bf16x8 avt[4];
      #pragma unroll
      for (int dt = 0; dt < 4; dt++)
        avt[dt] = *(const bf16x8*)(Vb + (dt * 16 + c) * 64 + (((t * 4 + g) ^ cs) << 3));
      bf16x8 bpt[2];
      #pragma unroll
      for (int iq = 0; iq < 2; iq++) {
        int row = iq * 16 + c;
        int bytecol = t * 64 + g * 16;
        uint32_t off = row * 128 + (((bytecol >> 4) ^ (row & 7)) << 4);
        bpt[iq] = *(const bf16x8*)(PwB + off);
      }
      #pragma unroll
      for (int dt = 0; dt < 4; dt++)
        #pragma unroll
        for (int iq = 0; iq < 2; iq++)
          OT[dt][iq] = MFMA_BF16(avt[dt], bpt[iq], OT[dt][iq], 0, 0, 0);
    }

    if (ti + 1 < ntiles) __syncthreads();      // stage(i+1) drained + all reads done
  }

  // l: per-lane partial covers kv rows {jt*16+g*4+r}; butterfly over g
  float inv[2];
  #pragma unroll
  for (int iq = 0; iq < 2; iq++) {
    float s = lv[iq];
    s += __shfl_xor(s, 16);
    s += __shfl_xor(s, 32);
    inv[iq] = 1.0f / s;
  }

  // write O: lane holds d = dt*16+g*4+{0..3}, q = Q0+iq*16+c -> 8B stores
  #pragma unroll
  for (int iq = 0; iq < 2; iq++) {
    const int q = Q0 + iq * 16 + c;
    unsigned short* orow = Outv + (size_t)(b * S_LEN + q) * (NHEADS * HDIM) + h * HDIM;
    #pragma unroll
    for (int dt = 0; dt < 4; dt++) {
      uint32_t u0 = __float_as_uint(OT[dt][iq][0] * inv[iq]) + 0x8000u;
      uint32_t u1 = __float_as_uint(OT[dt][iq][1] * inv[iq]) + 0x8000u;
      uint32_t u2 = __float_as_uint(OT[dt][iq][2] * inv[iq]) + 0x8000u;
      uint32_t u3 = __float_as_uint(OT[dt][iq][3] * inv[iq]) + 0x8000u;
      uint32_t lo = __builtin_amdgcn_perm(u1, u0, 0x07060302u);
      uint32_t hi = __builtin_amdgcn_perm(u3, u2, 0x07060302u);
      *(uint2*)(orow + dt * 16 + g * 4) = make_uint2(lo, hi);
    }
  }
}

extern "C" void kernel_launch(void* const* d_in, const int* in_sizes, int n_in,
                              void* d_out, int out_size, void* d_ws, size_t ws_size,
                              hipStream_t stream) {
  const float* x       = (const float*)d_in[0];
  // d_in[1] = mask (causal, implemented analytically)
  const float* cosb    = (const float*)d_in[2];
  const float* sinb    = (const float*)d_in[3];
  const float* Wq      = (const float*)d_in[4];
  const float* Wk      = (const float*)d_in[5];
  const float* Wv      = (const float*)d_in[6];
  const float* Wo      = (const float*)d_in[7];
  const float* q_scale = (const float*)d_in[8];
  const float* k_scale = (const float*)d_in[9];

  char* ws = (char*)d_ws;
  unsigned short* xb   = (unsigned short*)(ws);                       // 16 MiB: x bf16 [4096][2048]
  unsigned short* wcat = (unsigned short*)(ws + (16ull << 20));       // 12 MiB: Wt [3072][2048]
  unsigned short* wo_t = (unsigned short*)(ws + (28ull << 20));       //  8 MiB: Wo_t [2048][2048]
  unsigned short* qkv  = (unsigned short*)(ws + (36ull << 20));       // 24 MiB: QKV bf16 [4096][3072]
  unsigned short* qn   = (unsigned short*)(ws + (84ull << 20));       // 16 MiB: Q bf16 [b][h][s][d]
  unsigned short* kn   = (unsigned short*)(ws + (100ull << 20));      //  4 MiB: K bf16 [b][kv][s][d]
  unsigned short* vt   = (unsigned short*)(ws + (104ull << 20));      //  4 MiB: V^T bf16 [b][kv][d][s]
  unsigned short* vec  = (unsigned short*)(ws + (36ull << 20));       // alias qkv (dead after v_transpose)

  cast_x_kernel<<<8192, 256, 0, stream>>>(x, xb, 2097152);
  dim3 tb(32, 8);
  transpose_cast_wqkv<<<dim3(96, 64), tb, 0, stream>>>(Wq, Wk, Wv, wcat);
  transpose_cast<<<dim3(64, 64), tb, 0, stream>>>(Wo, wo_t, 2048, 2048);

  gemm_qkv_ring<<<dim3(12, 16), 512, 0, stream>>>(xb, wcat, qkv);
  norm_rope<<<10240, 256, 0, stream>>>(qkv, cosb, sinb, q_scale, k_scale, qn, kn);
  v_transpose<<<512, 256, 0, stream>>>(qkv, vt);
  attn_kernel<<<1024, 256, 0, stream>>>(qn, kn, vt, vec);
  gemm_nt<float><<<dim3(16, 32), 256, 0, stream>>>(vec, wo_t, (float*)d_out, 4096, 2048, 2048);
}

// Round 7
// 353.305 us; speedup vs baseline: 1.0057x; 1.0057x over previous
//
#include <hip/hip_runtime.h>
#include <hip/hip_bf16.h>
#include <stdint.h>

#define S_LEN   2048
#define DIN     2048
#define NHEADS  32
#define HDIM    64
#define NKV     8

typedef __bf16 bf16x8 __attribute__((ext_vector_type(8)));
typedef float  f32x4  __attribute__((ext_vector_type(4)));

#define AS1(p) ((__attribute__((address_space(1))) void*)(void*)(p))
#define AS3(p) ((__attribute__((address_space(3))) void*)(p))
#define MFMA_BF16 __builtin_amdgcn_mfma_f32_16x16x32_bf16

#if __has_builtin(__builtin_amdgcn_exp2f)
#define EXP2F(x) __builtin_amdgcn_exp2f(x)
#else
#define EXP2F(x) exp2f(x)
#endif

static __device__ __forceinline__ unsigned short f2bf(float f) {
  unsigned int x = __float_as_uint(f);
  return (unsigned short)((x + 0x7fffu + ((x >> 16) & 1u)) >> 16);
}
static __device__ __forceinline__ float bf2f(unsigned short u) {
  return __uint_as_float((unsigned int)u << 16);
}

// ---------------- cast x (fp32 -> bf16), vectorized ----------------
__global__ __launch_bounds__(256) void cast_x_kernel(const float* __restrict__ x,
                                                     unsigned short* __restrict__ xb, int n4) {
  int i = blockIdx.x * 256 + threadIdx.x;
  if (i >= n4) return;
  float4 f = ((const float4*)x)[i];
  ushort4 o = make_ushort4(f2bf(f.x), f2bf(f.y), f2bf(f.z), f2bf(f.w));
  ((ushort4*)xb)[i] = o;
}

// ---------------- transpose + cast: src fp32 [K][N] -> dst bf16 [N][K] ----------------
__global__ __launch_bounds__(256) void transpose_cast(const float* __restrict__ src,
                                                      unsigned short* __restrict__ dst,
                                                      int K, int N) {
  __shared__ float t[32][33];
  int n0 = blockIdx.x * 32, k0 = blockIdx.y * 32;
  int x = threadIdx.x, y = threadIdx.y;
  #pragma unroll
  for (int j = 0; j < 32; j += 8)
    t[y + j][x] = src[(size_t)(k0 + y + j) * N + n0 + x];
  __syncthreads();
  #pragma unroll
  for (int j = 0; j < 32; j += 8)
    dst[(size_t)(n0 + y + j) * K + k0 + x] = f2bf(t[x][y + j]);
}

// ---------------- fused W transpose: [Wq|Wk|Wv] -> wcat bf16 [3072][2048] ----------------
__global__ __launch_bounds__(256) void transpose_cast_wqkv(const float* __restrict__ Wq,
                                                           const float* __restrict__ Wk,
                                                           const float* __restrict__ Wv,
                                                           unsigned short* __restrict__ dst) {
  __shared__ float t[32][33];
  int n0 = blockIdx.x * 32, k0 = blockIdx.y * 32;   // n0 in [0,3072)
  const float* src; int col0, srcN;
  if (n0 < 2048)      { src = Wq; col0 = n0;        srcN = 2048; }
  else if (n0 < 2560) { src = Wk; col0 = n0 - 2048; srcN = 512; }
  else                { src = Wv; col0 = n0 - 2560; srcN = 512; }
  int x = threadIdx.x, y = threadIdx.y;
  #pragma unroll
  for (int j = 0; j < 32; j += 8)
    t[y + j][x] = src[(size_t)(k0 + y + j) * srcN + col0 + x];
  __syncthreads();
  #pragma unroll
  for (int j = 0; j < 32; j += 8)
    dst[(size_t)(n0 + y + j) * 2048 + k0 + x] = f2bf(t[x][y + j]);
}

// ---------------- ring bf16 NT GEMM: C[M][N] = A[M][K] * Bt[N][K]^T ----------------
// Composition of two verified pieces:
//  * gemm_nt's 128x128/BK32 layout + staging + (row>>1)&3 XOR swizzle
//    (measured SQ_LDS_BANK_CONFLICT = 0; round-6 ring's row&3 variant was a
//    4-way conflict per quarter-wave = 4.7M conflicts)
//  * round-6 ring sync (refcheck'd): 4-slot LDS ring, STAGE(t+3) at phase t,
//    counted s_waitcnt vmcnt(8) across raw s_barrier (tiles t+2,t+3 stay in
//    flight; never drains to 0 in the main loop), tail vmcnt(4)/(0).
// LDS 64 KiB -> 2 blocks/CU (m114 cross-block overlap); grid 768/512 = exact
// multiples of 256 CUs (the 256^2 ring's 192-block grid idled 25% of CUs).
template <typename OutT>
__global__ __launch_bounds__(256) void gemm_ring(const unsigned short* __restrict__ A,
                                                 const unsigned short* __restrict__ Bt,
                                                 OutT* __restrict__ C,
                                                 int M, int N, int K) {
  __shared__ alignas(16) unsigned short As[4][4096];   // 4 x 8 KiB (128 rows x 32 k)
  __shared__ alignas(16) unsigned short Bs[4][4096];
  const int tid = threadIdx.x;
  const int wave = tid >> 6, lane = tid & 63;
  const int g = lane >> 4, c = lane & 15;
  const int m0 = blockIdx.y * 128, n0 = blockIdx.x * 128;
  const int wm = (wave & 1) * 64, wn = (wave >> 1) * 64;

  f32x4 acc[4][4] = {};

  const int ch0 = wave * 2;
  const int p0 = ch0 * 64 + lane, p1 = p0 + 64;
  const int r0 = p0 >> 2, gc0 = ((p0 & 3) ^ ((r0 >> 1) & 3)) * 8;
  const int r1 = p1 >> 2, gc1 = ((p1 & 3) ^ ((r1 >> 1) & 3)) * 8;
  const unsigned short* a0 = A + (size_t)(m0 + r0) * K + gc0;
  const unsigned short* a1 = A + (size_t)(m0 + r1) * K + gc1;
  const unsigned short* b0 = Bt + (size_t)(n0 + r0) * K + gc0;
  const unsigned short* b1 = Bt + (size_t)(n0 + r1) * K + gc1;
  const int fswz = (c >> 1) & 3;   // consumer swizzle (rows wm,i*16 are mult of 16)

  const int NT = K >> 5;

  auto STAGE = [&](int t) {
    const int s = t & 3;
    const int ko = t * 32;
    __builtin_amdgcn_global_load_lds(AS1(a0 + ko), AS3(&As[s][ch0 * 512]), 16, 0, 0);
    __builtin_amdgcn_global_load_lds(AS1(a1 + ko), AS3(&As[s][ch0 * 512 + 512]), 16, 0, 0);
    __builtin_amdgcn_global_load_lds(AS1(b0 + ko), AS3(&Bs[s][ch0 * 512]), 16, 0, 0);
    __builtin_amdgcn_global_load_lds(AS1(b1 + ko), AS3(&Bs[s][ch0 * 512 + 512]), 16, 0, 0);
  };

  STAGE(0); STAGE(1); STAGE(2);                      // 12 loads in flight
  asm volatile("s_waitcnt vmcnt(8)" ::: "memory");   // tile 0 landed
  __builtin_amdgcn_s_barrier();

  for (int t = 0; t < NT; t++) {
    if (t + 3 < NT) STAGE(t + 3);    // slot (t+3)&3: its readers finished at t-1 barrier
    const int s = t & 3;
    bf16x8 af[4], bfr[4];
    #pragma unroll
    for (int i = 0; i < 4; i++)
      af[i] = *(const bf16x8*)(&As[s][(wm + i * 16 + c) * 32 + (g ^ fswz) * 8]);
    #pragma unroll
    for (int j = 0; j < 4; j++)
      bfr[j] = *(const bf16x8*)(&Bs[s][(wn + j * 16 + c) * 32 + (g ^ fswz) * 8]);
    __builtin_amdgcn_s_setprio(1);
    #pragma unroll
    for (int i = 0; i < 4; i++)
      #pragma unroll
      for (int j = 0; j < 4; j++)
        acc[i][j] = MFMA_BF16(af[i], bfr[j], acc[i][j], 0, 0, 0);
    __builtin_amdgcn_s_setprio(0);
    if (t + 3 < NT)      asm volatile("s_waitcnt vmcnt(8)" ::: "memory");  // tile t+1 landed
    else if (t + 2 < NT) asm volatile("s_waitcnt vmcnt(4)" ::: "memory");
    else                 asm volatile("s_waitcnt vmcnt(0)" ::: "memory");
    __builtin_amdgcn_s_barrier();
  }

  #pragma unroll
  for (int i = 0; i < 4; i++)
    #pragma unroll
    for (int j = 0; j < 4; j++)
      #pragma unroll
      for (int r = 0; r < 4; r++) {
        size_t idx = (size_t)(m0 + wm + i * 16 + g * 4 + r) * N + n0 + wn + j * 16 + c;
        if constexpr (sizeof(OutT) == 2) C[idx] = f2bf(acc[i][j][r]);
        else                             C[idx] = acc[i][j][r];
      }
}

// ---------------- RMSNorm + RoPE for Q and K heads (bf16 QKV input) ----------------
__global__ __launch_bounds__(256) void norm_rope(const unsigned short* __restrict__ QKV,
                                                 const float* __restrict__ cosb,
                                                 const float* __restrict__ sinb,
                                                 const float* __restrict__ q_scale,
                                                 const float* __restrict__ k_scale,
                                                 unsigned short* __restrict__ Qn,
                                                 unsigned short* __restrict__ Kn) {
  const int tid = threadIdx.x, w = tid >> 6, d = tid & 63;
  const float qs = q_scale[d], ks = k_scale[d];
  #pragma unroll
  for (int k = 0; k < 4; k++) {
    int task = blockIdx.x * 16 + w * 4 + k;
    const int hid = task % 40;
    const int row = task / 40;            // b*2048 + s
    const int b = row >> 11, s = row & 2047;
    float val, sc;
    if (hid < 32) {
      val = bf2f(QKV[(size_t)row * 3072 + hid * 64 + d]);
      sc = qs;
    } else {
      val = bf2f(QKV[(size_t)row * 3072 + 2048 + (hid - 32) * 64 + d]);
      sc = ks;
    }
    float v2 = val * val;
    #pragma unroll
    for (int off = 32; off; off >>= 1) v2 += __shfl_xor(v2, off);
    float t = val * (1.0f / sqrtf(v2 * (1.0f / 64.0f) + 1e-6f)) * sc;
    float partner = __shfl_xor(t, 32);
    float rot = (d < 32) ? -partner : partner;
    float o = t * cosb[s * 64 + d] + rot * sinb[s * 64 + d];
    if (hid < 32) o *= 0.18033688011112042f;   // fold softmax scale into Q
    unsigned short ob = f2bf(o);
    if (hid < 32) Qn[((size_t)(b * 32 + hid) * 2048 + s) * 64 + d] = ob;
    else          Kn[((size_t)(b * 8 + (hid - 32)) * 2048 + s) * 64 + d] = ob;
  }
}

// ---------------- V transpose: bf16 QKV V-cols -> Vt bf16 [b][kv][D][S] ----------------
__global__ __launch_bounds__(256) void v_transpose(const unsigned short* __restrict__ QKV,
                                                   unsigned short* __restrict__ Vt) {
  __shared__ unsigned int t[64][65];
  int bid = blockIdx.x;
  const int st = bid & 31, kv = (bid >> 5) & 7, b = bid >> 8;
  const int tid = threadIdx.x, lane = tid & 63, quad = tid >> 6;
  #pragma unroll
  for (int p = 0; p < 16; p++) {
    int sl = p * 4 + quad;
    t[sl][lane] = QKV[(size_t)(b * 2048 + st * 64 + sl) * 3072 + 2560 + kv * 64 + lane];
  }
  __syncthreads();
  size_t base = (size_t)(b * 8 + kv) * 64 * 2048;
  #pragma unroll
  for (int p = 0; p < 16; p++) {
    int dd = p * 4 + quad;
    Vt[base + (size_t)dd * 2048 + st * 64 + lane] = (unsigned short)t[lane][dd];
  }
}

// ---------------- causal flash attention v10 (unchanged from round 5) ----------------
__global__ __launch_bounds__(256, 3) void attn_kernel(const unsigned short* __restrict__ Qn,
                                                      const unsigned short* __restrict__ Kn,
                                                      const unsigned short* __restrict__ Vt,
                                                      unsigned short* __restrict__ Outv) {
  __shared__ alignas(16) unsigned short Ksh[2][4096];   // [buf][64 rows x 64 d]
  __shared__ alignas(16) unsigned short Vsh[2][4096];   // [buf][64 rows(d) x 64 kv]
  __shared__ alignas(16) char Psh[4][4352];             // per-wave P buffers

  const int tid = threadIdx.x, w = tid >> 6, lane = tid & 63;
  const int g = lane >> 4, c = lane & 15;
  const int cs = c & 7;
  const int rl = (lane >> 3) & 7;      // staging: row within 1KB chunk
  const int sl = lane & 7;             // staging: 16B slot within row
  const int swz = (sl ^ rl) << 3;      // pre-swizzled source column (elements)
  const int bid = blockIdx.x;                      // [0, 1024)
  const int qt = 63 - (bid >> 4);                  // longest blocks first
  const int rem = bid & 15;
  const int hg = rem & 7, b = rem >> 3;
  const int h = hg * 4 + w;
  const int Q0 = qt * 32;
  const unsigned short* Qp = Qn + ((size_t)(b * NHEADS + h) * S_LEN + Q0) * HDIM;
  const unsigned short* Kp = Kn + (size_t)(b * NKV + hg) * S_LEN * HDIM;
  const unsigned short* Vp = Vt + (size_t)(b * NKV + hg) * HDIM * S_LEN;  // [d][s]
  const int ntiles = (qt >> 1) + 1;
  char* PwB = Psh[w];                  // 32 rows x 128 B, swizzled

  // Q as B-operand: B[k=d][n=q], n = c, k = g*8+j (+t*32)
  bf16x8 bq[2][2];
  #pragma unroll
  for (int iq = 0; iq < 2; iq++)
    #pragma unroll
    for (int t = 0; t < 2; t++)
      bq[iq][t] = *(const bf16x8*)(Qp + (iq * 16 + c) * HDIM + t * 32 + g * 8);

  f32x4 OT[4][2] = {};          // O^T tiles: [dt][iq], row=d, col=q
  float lv[2] = {0.f, 0.f};     // per-lane l partials

  const int wr0 = w * 16;       // this wave's 16 staging rows

  // stage K rows [kv0+wr0, +16) and V^T rows [wr0, +16) of the kv window
  auto STAGE = [&](int kv0s, int bi) {
    #pragma unroll
    for (int q = 0; q < 2; q++) {
      const int rr = wr0 + q * 8;
      __builtin_amdgcn_global_load_lds(AS1(Kp + (size_t)(kv0s + rr + rl) * 64 + swz),
                                       AS3(&Ksh[bi][rr * 64]), 16, 0, 0);
      __builtin_amdgcn_global_load_lds(AS1(Vp + (size_t)(rr + rl) * 2048 + kv0s + swz),
                                       AS3(&Vsh[bi][rr * 64]), 16, 0, 0);
    }
  };

  STAGE(0, 0);
  __syncthreads();

  for (int ti = 0; ti < ntiles; ti++) {
    const int kv0 = ti * 64;
    const int cur = ti & 1;
    if (ti + 1 < ntiles) STAGE(kv0 + 64, cur ^ 1);

    const unsigned short* Kb = Ksh[cur];
    const unsigned short* Vb = Vsh[cur];

    // QK + softmax in two jt-pairs (Sx live = 16 regs)
    #pragma unroll
    for (int jb = 0; jb < 2; jb++) {
      bf16x8 akx[2][2];
      #pragma unroll
      for (int jt = 0; jt < 2; jt++)
        #pragma unroll
        for (int t = 0; t < 2; t++)
          akx[jt][t] = *(const bf16x8*)(Kb + ((jb * 2 + jt) * 16 + c) * 64 +
                                        (((t * 4 + g) ^ cs) << 3));
      f32x4 Sx[2][2] = {};
      #pragma unroll
      for (int t = 0; t < 2; t++)
        #pragma unroll
        for (int jt = 0; jt < 2; jt++)
          #pragma unroll
          for (int iq = 0; iq < 2; iq++)
            Sx[jt][iq] = MFMA_BF16(akx[jt][t], bq[iq][t], Sx[jt][iq], 0, 0, 0);

      if (ti == ntiles - 1) {   // only the final tile crosses the diagonal
        #pragma unroll
        for (int jt = 0; jt < 2; jt++)
          #pragma unroll
          for (int iq = 0; iq < 2; iq++)
            #pragma unroll
            for (int r = 0; r < 4; r++) {
              int kv = kv0 + (jb * 2 + jt) * 16 + g * 4 + r;
              int q  = Q0 + iq * 16 + c;
              if (kv > q) Sx[jt][iq][r] = -1e30f;
            }
      }

      // fixed-max softmax: p = exp2(s); accumulate l; pack P -> LDS (swizzled)
      #pragma unroll
      for (int jt = 0; jt < 2; jt++)
        #pragma unroll
        for (int iq = 0; iq < 2; iq++) {
          f32x4 p;
          #pragma unroll
          for (int r = 0; r < 4; r++) p[r] = EXP2F(Sx[jt][iq][r]);
          lv[iq] += (p[0] + p[1]) + (p[2] + p[3]);
          uint32_t u0 = __float_as_uint(p[0]) + 0x8000u;
          uint32_t u1 = __float_as_uint(p[1]) + 0x8000u;
          uint32_t u2 = __float_as_uint(p[2]) + 0x8000u;
          uint32_t u3 = __float_as_uint(p[3]) + 0x8000u;
          uint32_t lo = __builtin_amdgcn_perm(u1, u0, 0x07060302u);
          uint32_t hi = __builtin_amdgcn_perm(u3, u2, 0x07060302u);
          int row = iq * 16 + c;                       // local q
          int bytecol = (jb * 2 + jt) * 32 + g * 8;    // kv-contiguous bytes
          uint32_t off = row * 128 + (((bytecol >> 4) ^ (row & 7)) << 4) + (bytecol & 15);
          *(uint2*)(PwB + off) = make_uint2(lo, hi);
        }
    }

    __builtin_amdgcn_s_waitcnt(0xC07F);        // lgkmcnt(0): P writes visible

    // PV per t-half: V from LDS, P as B-operand B[k=kv][n=q]
    #pragma unroll
    for (int t = 0; t < 2; t++) {
      bf16x8 avt[4];
      #pragma unroll
      for (int dt = 0; dt < 4; dt++)
        avt[dt] = *(const bf16x8*)(Vb + (dt * 16 + c) * 64 + (((t * 4 + g) ^ cs) << 3));
      bf16x8 bpt[2];
      #pragma unroll
      for (int iq = 0; iq < 2; iq++) {
        int row = iq * 16 + c;
        int bytecol = t * 64 + g * 16;
        uint32_t off = row * 128 + (((bytecol >> 4) ^ (row & 7)) << 4);
        bpt[iq] = *(const bf16x8*)(PwB + off);
      }
      #pragma unroll
      for (int dt = 0; dt < 4; dt++)
        #pragma unroll
        for (int iq = 0; iq < 2; iq++)
          OT[dt][iq] = MFMA_BF16(avt[dt], bpt[iq], OT[dt][iq], 0, 0, 0);
    }

    if (ti + 1 < ntiles) __syncthreads();      // stage(i+1) drained + all reads done
  }

  // l: per-lane partial covers kv rows {jt*16+g*4+r}; butterfly over g
  float inv[2];
  #pragma unroll
  for (int iq = 0; iq < 2; iq++) {
    float s = lv[iq];
    s += __shfl_xor(s, 16);
    s += __shfl_xor(s, 32);
    inv[iq] = 1.0f / s;
  }

  // write O: lane holds d = dt*16+g*4+{0..3}, q = Q0+iq*16+c -> 8B stores
  #pragma unroll
  for (int iq = 0; iq < 2; iq++) {
    const int q = Q0 + iq * 16 + c;
    unsigned short* orow = Outv + (size_t)(b * S_LEN + q) * (NHEADS * HDIM) + h * HDIM;
    #pragma unroll
    for (int dt = 0; dt < 4; dt++) {
      uint32_t u0 = __float_as_uint(OT[dt][iq][0] * inv[iq]) + 0x8000u;
      uint32_t u1 = __float_as_uint(OT[dt][iq][1] * inv[iq]) + 0x8000u;
      uint32_t u2 = __float_as_uint(OT[dt][iq][2] * inv[iq]) + 0x8000u;
      uint32_t u3 = __float_as_uint(OT[dt][iq][3] * inv[iq]) + 0x8000u;
      uint32_t lo = __builtin_amdgcn_perm(u1, u0, 0x07060302u);
      uint32_t hi = __builtin_amdgcn_perm(u3, u2, 0x07060302u);
      *(uint2*)(orow + dt * 16 + g * 4) = make_uint2(lo, hi);
    }
  }
}

extern "C" void kernel_launch(void* const* d_in, const int* in_sizes, int n_in,
                              void* d_out, int out_size, void* d_ws, size_t ws_size,
                              hipStream_t stream) {
  const float* x       = (const float*)d_in[0];
  // d_in[1] = mask (causal, implemented analytically)
  const float* cosb    = (const float*)d_in[2];
  const float* sinb    = (const float*)d_in[3];
  const float* Wq      = (const float*)d_in[4];
  const float* Wk      = (const float*)d_in[5];
  const float* Wv      = (const float*)d_in[6];
  const float* Wo      = (const float*)d_in[7];
  const float* q_scale = (const float*)d_in[8];
  const float* k_scale = (const float*)d_in[9];

  char* ws = (char*)d_ws;
  unsigned short* xb   = (unsigned short*)(ws);                       // 16 MiB: x bf16 [4096][2048]
  unsigned short* wcat = (unsigned short*)(ws + (16ull << 20));       // 12 MiB: Wt [3072][2048]
  unsigned short* wo_t = (unsigned short*)(ws + (28ull << 20));       //  8 MiB: Wo_t [2048][2048]
  unsigned short* qkv  = (unsigned short*)(ws + (36ull << 20));       // 24 MiB: QKV bf16 [4096][3072]
  unsigned short* qn   = (unsigned short*)(ws + (84ull << 20));       // 16 MiB: Q bf16 [b][h][s][d]
  unsigned short* kn   = (unsigned short*)(ws + (100ull << 20));      //  4 MiB: K bf16 [b][kv][s][d]
  unsigned short* vt   = (unsigned short*)(ws + (104ull << 20));      //  4 MiB: V^T bf16 [b][kv][d][s]
  unsigned short* vec  = (unsigned short*)(ws + (36ull << 20));       // alias qkv (dead after v_transpose)

  cast_x_kernel<<<8192, 256, 0, stream>>>(x, xb, 2097152);
  dim3 tb(32, 8);
  transpose_cast_wqkv<<<dim3(96, 64), tb, 0, stream>>>(Wq, Wk, Wv, wcat);
  transpose_cast<<<dim3(64, 64), tb, 0, stream>>>(Wo, wo_t, 2048, 2048);

  gemm_ring<unsigned short><<<dim3(24, 32), 256, 0, stream>>>(xb, wcat, qkv, 4096, 3072, 2048);
  norm_rope<<<10240, 256, 0, stream>>>(qkv, cosb, sinb, q_scale, k_scale, qn, kn);
  v_transpose<<<512, 256, 0, stream>>>(qkv, vt);
  attn_kernel<<<1024, 256, 0, stream>>>(qn, kn, vt, vec);
  gemm_ring<float><<<dim3(16, 32), 256, 0, stream>>>(vec, wo_t, (float*)d_out, 4096, 2048, 2048);
}

// Round 8
// 326.566 us; speedup vs baseline: 1.0880x; 1.0819x over previous
//
#include <hip/hip_runtime.h>
#include <hip/hip_bf16.h>
#include <stdint.h>

#define S_LEN   2048
#define DIN     2048
#define NHEADS  32
#define HDIM    64
#define NKV     8

typedef __bf16 bf16x8 __attribute__((ext_vector_type(8)));
typedef float  f32x4  __attribute__((ext_vector_type(4)));

#define AS1(p) ((__attribute__((address_space(1))) void*)(void*)(p))
#define AS3(p) ((__attribute__((address_space(3))) void*)(p))
#define MFMA_BF16 __builtin_amdgcn_mfma_f32_16x16x32_bf16

#if __has_builtin(__builtin_amdgcn_exp2f)
#define EXP2F(x) __builtin_amdgcn_exp2f(x)
#else
#define EXP2F(x) exp2f(x)
#endif

static __device__ __forceinline__ unsigned short f2bf(float f) {
  unsigned int x = __float_as_uint(f);
  return (unsigned short)((x + 0x7fffu + ((x >> 16) & 1u)) >> 16);
}
static __device__ __forceinline__ float bf2f(unsigned short u) {
  return __uint_as_float((unsigned int)u << 16);
}

// ---------------- fused prep: cast x + transpose Wqkv + transpose Wo ----------------
// blocks [0,8192): cast x fp32->bf16 (2M float4s)
// blocks [8192,14336): transpose+cast [Wq|Wk|Wv] -> wcat bf16 [3072][2048]
// blocks [14336,18432): transpose+cast Wo -> wo_t bf16 [2048][2048]
// Inner loops byte-identical to the three verified kernels; flat 256 threads
// emulate the (32,8) shape via x=tid&31, y=tid>>5.
__global__ __launch_bounds__(256) void prep_kernel(const float* __restrict__ x,
                                                   const float* __restrict__ Wq,
                                                   const float* __restrict__ Wk,
                                                   const float* __restrict__ Wv,
                                                   const float* __restrict__ Wo,
                                                   unsigned short* __restrict__ xb,
                                                   unsigned short* __restrict__ wcat,
                                                   unsigned short* __restrict__ wo_t) {
  const int bid = blockIdx.x;
  if (bid < 8192) {                      // cast x: 8192*256 == 2097152 float4s exactly
    int i = bid * 256 + threadIdx.x;
    float4 f = ((const float4*)x)[i];
    ((ushort4*)xb)[i] = make_ushort4(f2bf(f.x), f2bf(f.y), f2bf(f.z), f2bf(f.w));
    return;
  }
  __shared__ float t[32][33];
  const int tx = threadIdx.x & 31, ty = threadIdx.x >> 5;
  const float* src; unsigned short* dst; int n0, k0, col0, srcN, dstK;
  if (bid < 14336) {                     // Wqkv transpose: grid (96,64)
    int b2 = bid - 8192;
    n0 = (b2 % 96) * 32; k0 = (b2 / 96) * 32;
    if (n0 < 2048)      { src = Wq; col0 = n0;        srcN = 2048; }
    else if (n0 < 2560) { src = Wk; col0 = n0 - 2048; srcN = 512; }
    else                { src = Wv; col0 = n0 - 2560; srcN = 512; }
    dst = wcat; dstK = 2048;
  } else {                               // Wo transpose: grid (64,64)
    int b3 = bid - 14336;
    n0 = (b3 % 64) * 32; k0 = (b3 / 64) * 32;
    src = Wo; col0 = n0; srcN = 2048; dst = wo_t; dstK = 2048;
  }
  #pragma unroll
  for (int j = 0; j < 32; j += 8)
    t[ty + j][tx] = src[(size_t)(k0 + ty + j) * srcN + col0 + tx];
  __syncthreads();
  #pragma unroll
  for (int j = 0; j < 32; j += 8)
    dst[(size_t)(n0 + ty + j) * dstK + k0 + tx] = f2bf(t[tx][ty + j]);
}

// ---------------- bf16 NT GEMM: C[M][N] = A[M][K] * Bt[N][K]^T (fp32 or bf16 out) ----
// m97 structure + XOR-swizzled LDS (swizzle realized via per-lane global address
// permutation in global_load_lds; consumer reads land 2-way/bank = free).
// REVERTED to the round-5 verified form: the 4-slot counted-vmcnt ring (rounds
// 6-7) measured SLOWER (96 vs 73.7 us) — 64KB LDS capped 2 blocks/CU, losing
// the m114 cross-block overlap that this 16KB structure gets at 4+ blocks/CU.
template <typename OutT>
__global__ __launch_bounds__(256) void gemm_nt(const unsigned short* __restrict__ A,
                                               const unsigned short* __restrict__ Bt,
                                               OutT* __restrict__ C,
                                               int M, int N, int K) {
  __shared__ alignas(16) unsigned short As[128 * 32];
  __shared__ alignas(16) unsigned short Bs[128 * 32];
  const int tid = threadIdx.x;
  const int wave = tid >> 6, lane = tid & 63;
  const int g = lane >> 4, c = lane & 15;
  const int m0 = blockIdx.y * 128, n0 = blockIdx.x * 128;
  const int wm = (wave & 1) * 64, wn = (wave >> 1) * 64;

  f32x4 acc[4][4] = {};

  const int ch0 = wave * 2;
  const int p0 = ch0 * 64 + lane, p1 = p0 + 64;
  const int r0 = p0 >> 2, gc0 = ((p0 & 3) ^ ((r0 >> 1) & 3)) * 8;
  const int r1 = p1 >> 2, gc1 = ((p1 & 3) ^ ((r1 >> 1) & 3)) * 8;
  const unsigned short* a0 = A + (size_t)(m0 + r0) * K + gc0;
  const unsigned short* a1 = A + (size_t)(m0 + r1) * K + gc1;
  const unsigned short* b0 = Bt + (size_t)(n0 + r0) * K + gc0;
  const unsigned short* b1 = Bt + (size_t)(n0 + r1) * K + gc1;
  const int fswz = (c >> 1) & 3;   // f(row) for consumer rows (wm,i*16 are mult of 16)

  for (int k0 = 0; k0 < K; k0 += 32) {
    __syncthreads();
    __builtin_amdgcn_global_load_lds(AS1(a0 + k0), AS3(As + ch0 * 512), 16, 0, 0);
    __builtin_amdgcn_global_load_lds(AS1(a1 + k0), AS3(As + ch0 * 512 + 512), 16, 0, 0);
    __builtin_amdgcn_global_load_lds(AS1(b0 + k0), AS3(Bs + ch0 * 512), 16, 0, 0);
    __builtin_amdgcn_global_load_lds(AS1(b1 + k0), AS3(Bs + ch0 * 512 + 512), 16, 0, 0);
    __builtin_amdgcn_s_waitcnt(0);
    __syncthreads();

    bf16x8 af[4], bfr[4];
    #pragma unroll
    for (int i = 0; i < 4; i++)
      af[i] = *(const bf16x8*)(As + (wm + i * 16 + c) * 32 + (g ^ fswz) * 8);
    #pragma unroll
    for (int j = 0; j < 4; j++)
      bfr[j] = *(const bf16x8*)(Bs + (wn + j * 16 + c) * 32 + (g ^ fswz) * 8);
    #pragma unroll
    for (int i = 0; i < 4; i++)
      #pragma unroll
      for (int j = 0; j < 4; j++)
        acc[i][j] = MFMA_BF16(af[i], bfr[j], acc[i][j], 0, 0, 0);
  }

  #pragma unroll
  for (int i = 0; i < 4; i++)
    #pragma unroll
    for (int j = 0; j < 4; j++)
      #pragma unroll
      for (int r = 0; r < 4; r++) {
        size_t idx = (size_t)(m0 + wm + i * 16 + g * 4 + r) * N + n0 + wn + j * 16 + c;
        if constexpr (sizeof(OutT) == 2) C[idx] = f2bf(acc[i][j][r]);
        else                             C[idx] = acc[i][j][r];
      }
}

// ---------------- fused norm_rope + v_transpose ----------------
// blocks [0,10240): RMSNorm+RoPE for Q/K heads (verbatim round-5 norm_rope)
// blocks [10240,10752): V transpose (verbatim round-5 v_transpose)
__global__ __launch_bounds__(256) void norm_rope_vt(const unsigned short* __restrict__ QKV,
                                                    const float* __restrict__ cosb,
                                                    const float* __restrict__ sinb,
                                                    const float* __restrict__ q_scale,
                                                    const float* __restrict__ k_scale,
                                                    unsigned short* __restrict__ Qn,
                                                    unsigned short* __restrict__ Kn,
                                                    unsigned short* __restrict__ Vt) {
  const int tid = threadIdx.x;
  if (blockIdx.x >= 10240) {             // ---- V transpose part ----
    __shared__ unsigned int t[64][65];
    int bid = blockIdx.x - 10240;
    const int st = bid & 31, kv = (bid >> 5) & 7, b = bid >> 8;
    const int lane = tid & 63, quad = tid >> 6;
    #pragma unroll
    for (int p = 0; p < 16; p++) {
      int sl = p * 4 + quad;
      t[sl][lane] = QKV[(size_t)(b * 2048 + st * 64 + sl) * 3072 + 2560 + kv * 64 + lane];
    }
    __syncthreads();
    size_t base = (size_t)(b * 8 + kv) * 64 * 2048;
    #pragma unroll
    for (int p = 0; p < 16; p++) {
      int dd = p * 4 + quad;
      Vt[base + (size_t)dd * 2048 + st * 64 + lane] = (unsigned short)t[lane][dd];
    }
    return;
  }
  // ---- norm+rope part ----
  const int w = tid >> 6, d = tid & 63;
  const float qs = q_scale[d], ks = k_scale[d];
  #pragma unroll
  for (int k = 0; k < 4; k++) {
    int task = blockIdx.x * 16 + w * 4 + k;
    const int hid = task % 40;
    const int row = task / 40;            // b*2048 + s
    const int b = row >> 11, s = row & 2047;
    float val, sc;
    if (hid < 32) {
      val = bf2f(QKV[(size_t)row * 3072 + hid * 64 + d]);
      sc = qs;
    } else {
      val = bf2f(QKV[(size_t)row * 3072 + 2048 + (hid - 32) * 64 + d]);
      sc = ks;
    }
    float v2 = val * val;
    #pragma unroll
    for (int off = 32; off; off >>= 1) v2 += __shfl_xor(v2, off);
    float t = val * (1.0f / sqrtf(v2 * (1.0f / 64.0f) + 1e-6f)) * sc;
    float partner = __shfl_xor(t, 32);
    float rot = (d < 32) ? -partner : partner;
    float o = t * cosb[s * 64 + d] + rot * sinb[s * 64 + d];
    if (hid < 32) o *= 0.18033688011112042f;   // fold softmax scale into Q
    unsigned short ob = f2bf(o);
    if (hid < 32) Qn[((size_t)(b * 32 + hid) * 2048 + s) * 64 + d] = ob;
    else          Kn[((size_t)(b * 8 + (hid - 32)) * 2048 + s) * 64 + d] = ob;
  }
}

// ---------------- causal flash attention v11 = v10 + setprio around MFMA (T5) ----
__global__ __launch_bounds__(256, 3) void attn_kernel(const unsigned short* __restrict__ Qn,
                                                      const unsigned short* __restrict__ Kn,
                                                      const unsigned short* __restrict__ Vt,
                                                      unsigned short* __restrict__ Outv) {
  __shared__ alignas(16) unsigned short Ksh[2][4096];   // [buf][64 rows x 64 d]
  __shared__ alignas(16) unsigned short Vsh[2][4096];   // [buf][64 rows(d) x 64 kv]
  __shared__ alignas(16) char Psh[4][4352];             // per-wave P buffers

  const int tid = threadIdx.x, w = tid >> 6, lane = tid & 63;
  const int g = lane >> 4, c = lane & 15;
  const int cs = c & 7;
  const int rl = (lane >> 3) & 7;      // staging: row within 1KB chunk
  const int sl = lane & 7;             // staging: 16B slot within row
  const int swz = (sl ^ rl) << 3;      // pre-swizzled source column (elements)
  const int bid = blockIdx.x;                      // [0, 1024)
  const int qt = 63 - (bid >> 4);                  // longest blocks first
  const int rem = bid & 15;
  const int hg = rem & 7, b = rem >> 3;
  const int h = hg * 4 + w;
  const int Q0 = qt * 32;
  const unsigned short* Qp = Qn + ((size_t)(b * NHEADS + h) * S_LEN + Q0) * HDIM;
  const unsigned short* Kp = Kn + (size_t)(b * NKV + hg) * S_LEN * HDIM;
  const unsigned short* Vp = Vt + (size_t)(b * NKV + hg) * HDIM * S_LEN;  // [d][s]
  const int ntiles = (qt >> 1) + 1;
  char* PwB = Psh[w];                  // 32 rows x 128 B, swizzled

  // Q as B-operand: B[k=d][n=q], n = c, k = g*8+j (+t*32)
  bf16x8 bq[2][2];
  #pragma unroll
  for (int iq = 0; iq < 2; iq++)
    #pragma unroll
    for (int t = 0; t < 2; t++)
      bq[iq][t] = *(const bf16x8*)(Qp + (iq * 16 + c) * HDIM + t * 32 + g * 8);

  f32x4 OT[4][2] = {};          // O^T tiles: [dt][iq], row=d, col=q
  float lv[2] = {0.f, 0.f};     // per-lane l partials

  const int wr0 = w * 16;       // this wave's 16 staging rows

  // stage K rows [kv0+wr0, +16) and V^T rows [wr0, +16) of the kv window
  auto STAGE = [&](int kv0s, int bi) {
    #pragma unroll
    for (int q = 0; q < 2; q++) {
      const int rr = wr0 + q * 8;
      __builtin_amdgcn_global_load_lds(AS1(Kp + (size_t)(kv0s + rr + rl) * 64 + swz),
                                       AS3(&Ksh[bi][rr * 64]), 16, 0, 0);
      __builtin_amdgcn_global_load_lds(AS1(Vp + (size_t)(rr + rl) * 2048 + kv0s + swz),
                                       AS3(&Vsh[bi][rr * 64]), 16, 0, 0);
    }
  };

  STAGE(0, 0);
  __syncthreads();

  for (int ti = 0; ti < ntiles; ti++) {
    const int kv0 = ti * 64;
    const int cur = ti & 1;
    if (ti + 1 < ntiles) STAGE(kv0 + 64, cur ^ 1);

    const unsigned short* Kb = Ksh[cur];
    const unsigned short* Vb = Vsh[cur];

    // QK + softmax in two jt-pairs (Sx live = 16 regs)
    #pragma unroll
    for (int jb = 0; jb < 2; jb++) {
      bf16x8 akx[2][2];
      #pragma unroll
      for (int jt = 0; jt < 2; jt++)
        #pragma unroll
        for (int t = 0; t < 2; t++)
          akx[jt][t] = *(const bf16x8*)(Kb + ((jb * 2 + jt) * 16 + c) * 64 +
                                        (((t * 4 + g) ^ cs) << 3));
      f32x4 Sx[2][2] = {};
      __builtin_amdgcn_s_setprio(1);
      #pragma unroll
      for (int t = 0; t < 2; t++)
        #pragma unroll
        for (int jt = 0; jt < 2; jt++)
          #pragma unroll
          for (int iq = 0; iq < 2; iq++)
            Sx[jt][iq] = MFMA_BF16(akx[jt][t], bq[iq][t], Sx[jt][iq], 0, 0, 0);
      __builtin_amdgcn_s_setprio(0);

      if (ti == ntiles - 1) {   // only the final tile crosses the diagonal
        #pragma unroll
        for (int jt = 0; jt < 2; jt++)
          #pragma unroll
          for (int iq = 0; iq < 2; iq++)
            #pragma unroll
            for (int r = 0; r < 4; r++) {
              int kv = kv0 + (jb * 2 + jt) * 16 + g * 4 + r;
              int q  = Q0 + iq * 16 + c;
              if (kv > q) Sx[jt][iq][r] = -1e30f;
            }
      }

      // fixed-max softmax: p = exp2(s); accumulate l; pack P -> LDS (swizzled)
      #pragma unroll
      for (int jt = 0; jt < 2; jt++)
        #pragma unroll
        for (int iq = 0; iq < 2; iq++) {
          f32x4 p;
          #pragma unroll
          for (int r = 0; r < 4; r++) p[r] = EXP2F(Sx[jt][iq][r]);
          lv[iq] += (p[0] + p[1]) + (p[2] + p[3]);
          uint32_t u0 = __float_as_uint(p[0]) + 0x8000u;
          uint32_t u1 = __float_as_uint(p[1]) + 0x8000u;
          uint32_t u2 = __float_as_uint(p[2]) + 0x8000u;
          uint32_t u3 = __float_as_uint(p[3]) + 0x8000u;
          uint32_t lo = __builtin_amdgcn_perm(u1, u0, 0x07060302u);
          uint32_t hi = __builtin_amdgcn_perm(u3, u2, 0x07060302u);
          int row = iq * 16 + c;                       // local q
          int bytecol = (jb * 2 + jt) * 32 + g * 8;    // kv-contiguous bytes
          uint32_t off = row * 128 + (((bytecol >> 4) ^ (row & 7)) << 4) + (bytecol & 15);
          *(uint2*)(PwB + off) = make_uint2(lo, hi);
        }
    }

    __builtin_amdgcn_s_waitcnt(0xC07F);        // lgkmcnt(0): P writes visible

    // PV per t-half: V from LDS, P as B-operand B[k=kv][n=q]
    #pragma unroll
    for (int t = 0; t < 2; t++) {
      bf16x8 avt[4];
      #pragma unroll
      for (int dt = 0; dt < 4; dt++)
        avt[dt] = *(const bf16x8*)(Vb + (dt * 16 + c) * 64 + (((t * 4 + g) ^ cs) << 3));
      bf16x8 bpt[2];
      #pragma unroll
      for (int iq = 0; iq < 2; iq++) {
        int row = iq * 16 + c;
        int bytecol = t * 64 + g * 16;
        uint32_t off = row * 128 + (((bytecol >> 4) ^ (row & 7)) << 4);
        bpt[iq] = *(const bf16x8*)(PwB + off);
      }
      __builtin_amdgcn_s_setprio(1);
      #pragma unroll
      for (int dt = 0; dt < 4; dt++)
        #pragma unroll
        for (int iq = 0; iq < 2; iq++)
          OT[dt][iq] = MFMA_BF16(avt[dt], bpt[iq], OT[dt][iq], 0, 0, 0);
      __builtin_amdgcn_s_setprio(0);
    }

    if (ti + 1 < ntiles) __syncthreads();      // stage(i+1) drained + all reads done
  }

  // l: per-lane partial covers kv rows {jt*16+g*4+r}; butterfly over g
  float inv[2];
  #pragma unroll
  for (int iq = 0; iq < 2; iq++) {
    float s = lv[iq];
    s += __shfl_xor(s, 16);
    s += __shfl_xor(s, 32);
    inv[iq] = 1.0f / s;
  }

  // write O: lane holds d = dt*16+g*4+{0..3}, q = Q0+iq*16+c -> 8B stores
  #pragma unroll
  for (int iq = 0; iq < 2; iq++) {
    const int q = Q0 + iq * 16 + c;
    unsigned short* orow = Outv + (size_t)(b * S_LEN + q) * (NHEADS * HDIM) + h * HDIM;
    #pragma unroll
    for (int dt = 0; dt < 4; dt++) {
      uint32_t u0 = __float_as_uint(OT[dt][iq][0] * inv[iq]) + 0x8000u;
      uint32_t u1 = __float_as_uint(OT[dt][iq][1] * inv[iq]) + 0x8000u;
      uint32_t u2 = __float_as_uint(OT[dt][iq][2] * inv[iq]) + 0x8000u;
      uint32_t u3 = __float_as_uint(OT[dt][iq][3] * inv[iq]) + 0x8000u;
      uint32_t lo = __builtin_amdgcn_perm(u1, u0, 0x07060302u);
      uint32_t hi = __builtin_amdgcn_perm(u3, u2, 0x07060302u);
      *(uint2*)(orow + dt * 16 + g * 4) = make_uint2(lo, hi);
    }
  }
}

extern "C" void kernel_launch(void* const* d_in, const int* in_sizes, int n_in,
                              void* d_out, int out_size, void* d_ws, size_t ws_size,
                              hipStream_t stream) {
  const float* x       = (const float*)d_in[0];
  // d_in[1] = mask (causal, implemented analytically)
  const float* cosb    = (const float*)d_in[2];
  const float* sinb    = (const float*)d_in[3];
  const float* Wq      = (const float*)d_in[4];
  const float* Wk      = (const float*)d_in[5];
  const float* Wv      = (const float*)d_in[6];
  const float* Wo      = (const float*)d_in[7];
  const float* q_scale = (const float*)d_in[8];
  const float* k_scale = (const float*)d_in[9];

  char* ws = (char*)d_ws;
  unsigned short* xb   = (unsigned short*)(ws);                       // 16 MiB: x bf16 [4096][2048]
  unsigned short* wcat = (unsigned short*)(ws + (16ull << 20));       // 12 MiB: Wt [3072][2048]
  unsigned short* wo_t = (unsigned short*)(ws + (28ull << 20));       //  8 MiB: Wo_t [2048][2048]
  unsigned short* qkv  = (unsigned short*)(ws + (36ull << 20));       // 24 MiB: QKV bf16 [4096][3072]
  unsigned short* qn   = (unsigned short*)(ws + (84ull << 20));       // 16 MiB: Q bf16 [b][h][s][d]
  unsigned short* kn   = (unsigned short*)(ws + (100ull << 20));      //  4 MiB: K bf16 [b][kv][s][d]
  unsigned short* vt   = (unsigned short*)(ws + (104ull << 20));      //  4 MiB: V^T bf16 [b][kv][d][s]
  unsigned short* vec  = (unsigned short*)(ws + (36ull << 20));       // alias qkv (dead after v_transpose)

  prep_kernel<<<18432, 256, 0, stream>>>(x, Wq, Wk, Wv, Wo, xb, wcat, wo_t);
  gemm_nt<unsigned short><<<dim3(24, 32), 256, 0, stream>>>(xb, wcat, qkv, 4096, 3072, 2048);
  norm_rope_vt<<<10752, 256, 0, stream>>>(qkv, cosb, sinb, q_scale, k_scale, qn, kn, vt);
  attn_kernel<<<1024, 256, 0, stream>>>(qn, kn, vt, vec);
  gemm_nt<float><<<dim3(16, 32), 256, 0, stream>>>(vec, wo_t, (float*)d_out, 4096, 2048, 2048);
}

// Round 9
// 315.030 us; speedup vs baseline: 1.1278x; 1.0366x over previous
//
#include <hip/hip_runtime.h>
#include <hip/hip_bf16.h>
#include <stdint.h>

#define S_LEN   2048
#define DIN     2048
#define NHEADS  32
#define HDIM    64
#define NKV     8

typedef __bf16 bf16x8 __attribute__((ext_vector_type(8)));
typedef float  f32x4  __attribute__((ext_vector_type(4)));

#define AS1(p) ((__attribute__((address_space(1))) void*)(void*)(p))
#define AS3(p) ((__attribute__((address_space(3))) void*)(p))
#define MFMA_BF16 __builtin_amdgcn_mfma_f32_16x16x32_bf16

#if __has_builtin(__builtin_amdgcn_exp2f)
#define EXP2F(x) __builtin_amdgcn_exp2f(x)
#else
#define EXP2F(x) exp2f(x)
#endif

static __device__ __forceinline__ unsigned short f2bf(float f) {
  unsigned int x = __float_as_uint(f);
  return (unsigned short)((x + 0x7fffu + ((x >> 16) & 1u)) >> 16);
}
static __device__ __forceinline__ float bf2f(unsigned short u) {
  return __uint_as_float((unsigned int)u << 16);
}

// ---------------- fused prep: cast x + transpose Wqkv + transpose Wo ----------------
// blocks [0,8192): cast x fp32->bf16 (2M float4s)
// blocks [8192,14336): transpose+cast [Wq|Wk|Wv] -> wcat bf16 [3072][2048]
// blocks [14336,18432): transpose+cast Wo -> wo_t bf16 [2048][2048]
__global__ __launch_bounds__(256) void prep_kernel(const float* __restrict__ x,
                                                   const float* __restrict__ Wq,
                                                   const float* __restrict__ Wk,
                                                   const float* __restrict__ Wv,
                                                   const float* __restrict__ Wo,
                                                   unsigned short* __restrict__ xb,
                                                   unsigned short* __restrict__ wcat,
                                                   unsigned short* __restrict__ wo_t) {
  const int bid = blockIdx.x;
  if (bid < 8192) {                      // cast x: 8192*256 == 2097152 float4s exactly
    int i = bid * 256 + threadIdx.x;
    float4 f = ((const float4*)x)[i];
    ((ushort4*)xb)[i] = make_ushort4(f2bf(f.x), f2bf(f.y), f2bf(f.z), f2bf(f.w));
    return;
  }
  __shared__ float t[32][33];
  const int tx = threadIdx.x & 31, ty = threadIdx.x >> 5;
  const float* src; unsigned short* dst; int n0, k0, col0, srcN, dstK;
  if (bid < 14336) {                     // Wqkv transpose: grid (96,64)
    int b2 = bid - 8192;
    n0 = (b2 % 96) * 32; k0 = (b2 / 96) * 32;
    if (n0 < 2048)      { src = Wq; col0 = n0;        srcN = 2048; }
    else if (n0 < 2560) { src = Wk; col0 = n0 - 2048; srcN = 512; }
    else                { src = Wv; col0 = n0 - 2560; srcN = 512; }
    dst = wcat; dstK = 2048;
  } else {                               // Wo transpose: grid (64,64)
    int b3 = bid - 14336;
    n0 = (b3 % 64) * 32; k0 = (b3 / 64) * 32;
    src = Wo; col0 = n0; srcN = 2048; dst = wo_t; dstK = 2048;
  }
  #pragma unroll
  for (int j = 0; j < 32; j += 8)
    t[ty + j][tx] = src[(size_t)(k0 + ty + j) * srcN + col0 + tx];
  __syncthreads();
  #pragma unroll
  for (int j = 0; j < 32; j += 8)
    dst[(size_t)(n0 + ty + j) * dstK + k0 + tx] = f2bf(t[tx][ty + j]);
}

// ---------------- bf16 NT GEMM, BK=64: C[M][N] = A[M][K] * Bt[N][K]^T ----------------
// m97 structure with the K-step doubled: two INDEPENDENT 16KB LDS halves, each
// byte-identical to the verified BK=32 layout ((row>>1)&3 XOR swizzle via
// pre-permuted global source, conflict-free measured). One stage(8 loads)->
// drain->barrier per 64 k instead of two per 64 k: latency exposures and
// barrier pairs halved (64->32 per block); 32 MFMA amortize each barrier.
// LDS 32KB (<=5 blocks/CU, not the limiter) keeps occupancy unchanged --
// the m132 BK=128 regression was the 64KB occupancy cliff, which this avoids.
template <typename OutT>
__global__ __launch_bounds__(256) void gemm_nt(const unsigned short* __restrict__ A,
                                               const unsigned short* __restrict__ Bt,
                                               OutT* __restrict__ C,
                                               int M, int N, int K) {
  __shared__ alignas(16) unsigned short As[2][4096];   // [half][128 rows x 32 k]
  __shared__ alignas(16) unsigned short Bs[2][4096];
  const int tid = threadIdx.x;
  const int wave = tid >> 6, lane = tid & 63;
  const int g = lane >> 4, c = lane & 15;
  const int m0 = blockIdx.y * 128, n0 = blockIdx.x * 128;
  const int wm = (wave & 1) * 64, wn = (wave >> 1) * 64;

  f32x4 acc[4][4] = {};

  const int ch0 = wave * 2;
  const int p0 = ch0 * 64 + lane, p1 = p0 + 64;
  const int r0 = p0 >> 2, gc0 = ((p0 & 3) ^ ((r0 >> 1) & 3)) * 8;
  const int r1 = p1 >> 2, gc1 = ((p1 & 3) ^ ((r1 >> 1) & 3)) * 8;
  const unsigned short* a0 = A + (size_t)(m0 + r0) * K + gc0;
  const unsigned short* a1 = A + (size_t)(m0 + r1) * K + gc1;
  const unsigned short* b0 = Bt + (size_t)(n0 + r0) * K + gc0;
  const unsigned short* b1 = Bt + (size_t)(n0 + r1) * K + gc1;
  const int fswz = (c >> 1) & 3;   // f(row) for consumer rows (wm,i*16 are mult of 16)

  for (int k0 = 0; k0 < K; k0 += 64) {
    __syncthreads();
    __builtin_amdgcn_global_load_lds(AS1(a0 + k0), AS3(&As[0][ch0 * 512]), 16, 0, 0);
    __builtin_amdgcn_global_load_lds(AS1(a1 + k0), AS3(&As[0][ch0 * 512 + 512]), 16, 0, 0);
    __builtin_amdgcn_global_load_lds(AS1(b0 + k0), AS3(&Bs[0][ch0 * 512]), 16, 0, 0);
    __builtin_amdgcn_global_load_lds(AS1(b1 + k0), AS3(&Bs[0][ch0 * 512 + 512]), 16, 0, 0);
    __builtin_amdgcn_global_load_lds(AS1(a0 + k0 + 32), AS3(&As[1][ch0 * 512]), 16, 0, 0);
    __builtin_amdgcn_global_load_lds(AS1(a1 + k0 + 32), AS3(&As[1][ch0 * 512 + 512]), 16, 0, 0);
    __builtin_amdgcn_global_load_lds(AS1(b0 + k0 + 32), AS3(&Bs[1][ch0 * 512]), 16, 0, 0);
    __builtin_amdgcn_global_load_lds(AS1(b1 + k0 + 32), AS3(&Bs[1][ch0 * 512 + 512]), 16, 0, 0);
    __builtin_amdgcn_s_waitcnt(0);
    __syncthreads();

    #pragma unroll
    for (int h = 0; h < 2; h++) {
      bf16x8 af[4], bfr[4];
      #pragma unroll
      for (int i = 0; i < 4; i++)
        af[i] = *(const bf16x8*)(&As[h][(wm + i * 16 + c) * 32 + (g ^ fswz) * 8]);
      #pragma unroll
      for (int j = 0; j < 4; j++)
        bfr[j] = *(const bf16x8*)(&Bs[h][(wn + j * 16 + c) * 32 + (g ^ fswz) * 8]);
      #pragma unroll
      for (int i = 0; i < 4; i++)
        #pragma unroll
        for (int j = 0; j < 4; j++)
          acc[i][j] = MFMA_BF16(af[i], bfr[j], acc[i][j], 0, 0, 0);
    }
  }

  #pragma unroll
  for (int i = 0; i < 4; i++)
    #pragma unroll
    for (int j = 0; j < 4; j++)
      #pragma unroll
      for (int r = 0; r < 4; r++) {
        size_t idx = (size_t)(m0 + wm + i * 16 + g * 4 + r) * N + n0 + wn + j * 16 + c;
        if constexpr (sizeof(OutT) == 2) C[idx] = f2bf(acc[i][j][r]);
        else                             C[idx] = acc[i][j][r];
      }
}

// ---------------- fused norm_rope + v_transpose ----------------
// blocks [0,10240): RMSNorm+RoPE for Q/K heads; blocks [10240,10752): V transpose
__global__ __launch_bounds__(256) void norm_rope_vt(const unsigned short* __restrict__ QKV,
                                                    const float* __restrict__ cosb,
                                                    const float* __restrict__ sinb,
                                                    const float* __restrict__ q_scale,
                                                    const float* __restrict__ k_scale,
                                                    unsigned short* __restrict__ Qn,
                                                    unsigned short* __restrict__ Kn,
                                                    unsigned short* __restrict__ Vt) {
  const int tid = threadIdx.x;
  if (blockIdx.x >= 10240) {             // ---- V transpose part ----
    __shared__ unsigned int t[64][65];
    int bid = blockIdx.x - 10240;
    const int st = bid & 31, kv = (bid >> 5) & 7, b = bid >> 8;
    const int lane = tid & 63, quad = tid >> 6;
    #pragma unroll
    for (int p = 0; p < 16; p++) {
      int sl = p * 4 + quad;
      t[sl][lane] = QKV[(size_t)(b * 2048 + st * 64 + sl) * 3072 + 2560 + kv * 64 + lane];
    }
    __syncthreads();
    size_t base = (size_t)(b * 8 + kv) * 64 * 2048;
    #pragma unroll
    for (int p = 0; p < 16; p++) {
      int dd = p * 4 + quad;
      Vt[base + (size_t)dd * 2048 + st * 64 + lane] = (unsigned short)t[lane][dd];
    }
    return;
  }
  // ---- norm+rope part ----
  const int w = tid >> 6, d = tid & 63;
  const float qs = q_scale[d], ks = k_scale[d];
  #pragma unroll
  for (int k = 0; k < 4; k++) {
    int task = blockIdx.x * 16 + w * 4 + k;
    const int hid = task % 40;
    const int row = task / 40;            // b*2048 + s
    const int b = row >> 11, s = row & 2047;
    float val, sc;
    if (hid < 32) {
      val = bf2f(QKV[(size_t)row * 3072 + hid * 64 + d]);
      sc = qs;
    } else {
      val = bf2f(QKV[(size_t)row * 3072 + 2048 + (hid - 32) * 64 + d]);
      sc = ks;
    }
    float v2 = val * val;
    #pragma unroll
    for (int off = 32; off; off >>= 1) v2 += __shfl_xor(v2, off);
    float t = val * (1.0f / sqrtf(v2 * (1.0f / 64.0f) + 1e-6f)) * sc;
    float partner = __shfl_xor(t, 32);
    float rot = (d < 32) ? -partner : partner;
    float o = t * cosb[s * 64 + d] + rot * sinb[s * 64 + d];
    if (hid < 32) o *= 0.18033688011112042f;   // fold softmax scale into Q
    unsigned short ob = f2bf(o);
    if (hid < 32) Qn[((size_t)(b * 32 + hid) * 2048 + s) * 64 + d] = ob;
    else          Kn[((size_t)(b * 8 + (hid - 32)) * 2048 + s) * 64 + d] = ob;
  }
}

// ---------------- causal flash attention v11 (unchanged from round 8) ----------------
__global__ __launch_bounds__(256, 3) void attn_kernel(const unsigned short* __restrict__ Qn,
                                                      const unsigned short* __restrict__ Kn,
                                                      const unsigned short* __restrict__ Vt,
                                                      unsigned short* __restrict__ Outv) {
  __shared__ alignas(16) unsigned short Ksh[2][4096];   // [buf][64 rows x 64 d]
  __shared__ alignas(16) unsigned short Vsh[2][4096];   // [buf][64 rows(d) x 64 kv]
  __shared__ alignas(16) char Psh[4][4352];             // per-wave P buffers

  const int tid = threadIdx.x, w = tid >> 6, lane = tid & 63;
  const int g = lane >> 4, c = lane & 15;
  const int cs = c & 7;
  const int rl = (lane >> 3) & 7;      // staging: row within 1KB chunk
  const int sl = lane & 7;             // staging: 16B slot within row
  const int swz = (sl ^ rl) << 3;      // pre-swizzled source column (elements)
  const int bid = blockIdx.x;                      // [0, 1024)
  const int qt = 63 - (bid >> 4);                  // longest blocks first
  const int rem = bid & 15;
  const int hg = rem & 7, b = rem >> 3;
  const int h = hg * 4 + w;
  const int Q0 = qt * 32;
  const unsigned short* Qp = Qn + ((size_t)(b * NHEADS + h) * S_LEN + Q0) * HDIM;
  const unsigned short* Kp = Kn + (size_t)(b * NKV + hg) * S_LEN * HDIM;
  const unsigned short* Vp = Vt + (size_t)(b * NKV + hg) * HDIM * S_LEN;  // [d][s]
  const int ntiles = (qt >> 1) + 1;
  char* PwB = Psh[w];                  // 32 rows x 128 B, swizzled

  // Q as B-operand: B[k=d][n=q], n = c, k = g*8+j (+t*32)
  bf16x8 bq[2][2];
  #pragma unroll
  for (int iq = 0; iq < 2; iq++)
    #pragma unroll
    for (int t = 0; t < 2; t++)
      bq[iq][t] = *(const bf16x8*)(Qp + (iq * 16 + c) * HDIM + t * 32 + g * 8);

  f32x4 OT[4][2] = {};          // O^T tiles: [dt][iq], row=d, col=q
  float lv[2] = {0.f, 0.f};     // per-lane l partials

  const int wr0 = w * 16;       // this wave's 16 staging rows

  // stage K rows [kv0+wr0, +16) and V^T rows [wr0, +16) of the kv window
  auto STAGE = [&](int kv0s, int bi) {
    #pragma unroll
    for (int q = 0; q < 2; q++) {
      const int rr = wr0 + q * 8;
      __builtin_amdgcn_global_load_lds(AS1(Kp + (size_t)(kv0s + rr + rl) * 64 + swz),
                                       AS3(&Ksh[bi][rr * 64]), 16, 0, 0);
      __builtin_amdgcn_global_load_lds(AS1(Vp + (size_t)(rr + rl) * 2048 + kv0s + swz),
                                       AS3(&Vsh[bi][rr * 64]), 16, 0, 0);
    }
  };

  STAGE(0, 0);
  __syncthreads();

  for (int ti = 0; ti < ntiles; ti++) {
    const int kv0 = ti * 64;
    const int cur = ti & 1;
    if (ti + 1 < ntiles) STAGE(kv0 + 64, cur ^ 1);

    const unsigned short* Kb = Ksh[cur];
    const unsigned short* Vb = Vsh[cur];

    // QK + softmax in two jt-pairs (Sx live = 16 regs)
    #pragma unroll
    for (int jb = 0; jb < 2; jb++) {
      bf16x8 akx[2][2];
      #pragma unroll
      for (int jt = 0; jt < 2; jt++)
        #pragma unroll
        for (int t = 0; t < 2; t++)
          akx[jt][t] = *(const bf16x8*)(Kb + ((jb * 2 + jt) * 16 + c) * 64 +
                                        (((t * 4 + g) ^ cs) << 3));
      f32x4 Sx[2][2] = {};
      __builtin_amdgcn_s_setprio(1);
      #pragma unroll
      for (int t = 0; t < 2; t++)
        #pragma unroll
        for (int jt = 0; jt < 2; jt++)
          #pragma unroll
          for (int iq = 0; iq < 2; iq++)
            Sx[jt][iq] = MFMA_BF16(akx[jt][t], bq[iq][t], Sx[jt][iq], 0, 0, 0);
      __builtin_amdgcn_s_setprio(0);

      if (ti == ntiles - 1) {   // only the final tile crosses the diagonal
        #pragma unroll
        for (int jt = 0; jt < 2; jt++)
          #pragma unroll
          for (int iq = 0; iq < 2; iq++)
            #pragma unroll
            for (int r = 0; r < 4; r++) {
              int kv = kv0 + (jb * 2 + jt) * 16 + g * 4 + r;
              int q  = Q0 + iq * 16 + c;
              if (kv > q) Sx[jt][iq][r] = -1e30f;
            }
      }

      // fixed-max softmax: p = exp2(s); accumulate l; pack P -> LDS (swizzled)
      #pragma unroll
      for (int jt = 0; jt < 2; jt++)
        #pragma unroll
        for (int iq = 0; iq < 2; iq++) {
          f32x4 p;
          #pragma unroll
          for (int r = 0; r < 4; r++) p[r] = EXP2F(Sx[jt][iq][r]);
          lv[iq] += (p[0] + p[1]) + (p[2] + p[3]);
          uint32_t u0 = __float_as_uint(p[0]) + 0x8000u;
          uint32_t u1 = __float_as_uint(p[1]) + 0x8000u;
          uint32_t u2 = __float_as_uint(p[2]) + 0x8000u;
          uint32_t u3 = __float_as_uint(p[3]) + 0x8000u;
          uint32_t lo = __builtin_amdgcn_perm(u1, u0, 0x07060302u);
          uint32_t hi = __builtin_amdgcn_perm(u3, u2, 0x07060302u);
          int row = iq * 16 + c;                       // local q
          int bytecol = (jb * 2 + jt) * 32 + g * 8;    // kv-contiguous bytes
          uint32_t off = row * 128 + (((bytecol >> 4) ^ (row & 7)) << 4) + (bytecol & 15);
          *(uint2*)(PwB + off) = make_uint2(lo, hi);
        }
    }

    __builtin_amdgcn_s_waitcnt(0xC07F);        // lgkmcnt(0): P writes visible

    // PV per t-half: V from LDS, P as B-operand B[k=kv][n=q]
    #pragma unroll
    for (int t = 0; t < 2; t++) {
      bf16x8 avt[4];
      #pragma unroll
      for (int dt = 0; dt < 4; dt++)
        avt[dt] = *(const bf16x8*)(Vb + (dt * 16 + c) * 64 + (((t * 4 + g) ^ cs) << 3));
      bf16x8 bpt[2];
      #pragma unroll
      for (int iq = 0; iq < 2; iq++) {
        int row = iq * 16 + c;
        int bytecol = t * 64 + g * 16;
        uint32_t off = row * 128 + (((bytecol >> 4) ^ (row & 7)) << 4);
        bpt[iq] = *(const bf16x8*)(PwB + off);
      }
      __builtin_amdgcn_s_setprio(1);
      #pragma unroll
      for (int dt = 0; dt < 4; dt++)
        #pragma unroll
        for (int iq = 0; iq < 2; iq++)
          OT[dt][iq] = MFMA_BF16(avt[dt], bpt[iq], OT[dt][iq], 0, 0, 0);
      __builtin_amdgcn_s_setprio(0);
    }

    if (ti + 1 < ntiles) __syncthreads();      // stage(i+1) drained + all reads done
  }

  // l: per-lane partial covers kv rows {jt*16+g*4+r}; butterfly over g
  float inv[2];
  #pragma unroll
  for (int iq = 0; iq < 2; iq++) {
    float s = lv[iq];
    s += __shfl_xor(s, 16);
    s += __shfl_xor(s, 32);
    inv[iq] = 1.0f / s;
  }

  // write O: lane holds d = dt*16+g*4+{0..3}, q = Q0+iq*16+c -> 8B stores
  #pragma unroll
  for (int iq = 0; iq < 2; iq++) {
    const int q = Q0 + iq * 16 + c;
    unsigned short* orow = Outv + (size_t)(b * S_LEN + q) * (NHEADS * HDIM) + h * HDIM;
    #pragma unroll
    for (int dt = 0; dt < 4; dt++) {
      uint32_t u0 = __float_as_uint(OT[dt][iq][0] * inv[iq]) + 0x8000u;
      uint32_t u1 = __float_as_uint(OT[dt][iq][1] * inv[iq]) + 0x8000u;
      uint32_t u2 = __float_as_uint(OT[dt][iq][2] * inv[iq]) + 0x8000u;
      uint32_t u3 = __float_as_uint(OT[dt][iq][3] * inv[iq]) + 0x8000u;
      uint32_t lo = __builtin_amdgcn_perm(u1, u0, 0x07060302u);
      uint32_t hi = __builtin_amdgcn_perm(u3, u2, 0x07060302u);
      *(uint2*)(orow + dt * 16 + g * 4) = make_uint2(lo, hi);
    }
  }
}

extern "C" void kernel_launch(void* const* d_in, const int* in_sizes, int n_in,
                              void* d_out, int out_size, void* d_ws, size_t ws_size,
                              hipStream_t stream) {
  const float* x       = (const float*)d_in[0];
  // d_in[1] = mask (causal, implemented analytically)
  const float* cosb    = (const float*)d_in[2];
  const float* sinb    = (const float*)d_in[3];
  const float* Wq      = (const float*)d_in[4];
  const float* Wk      = (const float*)d_in[5];
  const float* Wv      = (const float*)d_in[6];
  const float* Wo      = (const float*)d_in[7];
  const float* q_scale = (const float*)d_in[8];
  const float* k_scale = (const float*)d_in[9];

  char* ws = (char*)d_ws;
  unsigned short* xb   = (unsigned short*)(ws);                       // 16 MiB: x bf16 [4096][2048]
  unsigned short* wcat = (unsigned short*)(ws + (16ull << 20));       // 12 MiB: Wt [3072][2048]
  unsigned short* wo_t = (unsigned short*)(ws + (28ull << 20));       //  8 MiB: Wo_t [2048][2048]
  unsigned short* qkv  = (unsigned short*)(ws + (36ull << 20));       // 24 MiB: QKV bf16 [4096][3072]
  unsigned short* qn   = (unsigned short*)(ws + (84ull << 20));       // 16 MiB: Q bf16 [b][h][s][d]
  unsigned short* kn   = (unsigned short*)(ws + (100ull << 20));      //  4 MiB: K bf16 [b][kv][s][d]
  unsigned short* vt   = (unsigned short*)(ws + (104ull << 20));      //  4 MiB: V^T bf16 [b][kv][d][s]
  unsigned short* vec  = (unsigned short*)(ws + (36ull << 20));       // alias qkv (dead after v_transpose)

  prep_kernel<<<18432, 256, 0, stream>>>(x, Wq, Wk, Wv, Wo, xb, wcat, wo_t);
  gemm_nt<unsigned short><<<dim3(24, 32), 256, 0, stream>>>(xb, wcat, qkv, 4096, 3072, 2048);
  norm_rope_vt<<<10752, 256, 0, stream>>>(qkv, cosb, sinb, q_scale, k_scale, qn, kn, vt);
  attn_kernel<<<1024, 256, 0, stream>>>(qn, kn, vt, vec);
  gemm_nt<float><<<dim3(16, 32), 256, 0, stream>>>(vec, wo_t, (float*)d_out, 4096, 2048, 2048);
}